// Round 9
// baseline (169.858 us; speedup 1.0000x reference)
//
#include <hip/hip_runtime.h>
#include <hip/hip_bf16.h>

#define DIM   256
#define DH    64
#define NKS   64      // K_SLOTS
#define NH    4       // HEADS
#define SEQ   32768

typedef float f32x4  __attribute__((ext_vector_type(4)));
typedef short bf16x8 __attribute__((ext_vector_type(8)));

__device__ __forceinline__ unsigned short f2bf(float f) {
    union { __hip_bfloat16 b; unsigned short u; } v;
    v.b = __float2bfloat16(f);
    return v.u;
}
__device__ __forceinline__ unsigned int f2bf2(float lo, float hi) {
    return (unsigned int)f2bf(lo) | ((unsigned int)f2bf(hi) << 16);
}
// raw barrier: NO vmcnt drain (HIP __syncthreads would force vmcnt(0)).
// lgkmcnt(0) publishes this wave's LDS writes; "memory" clobber pins
// compiler ordering of LDS/global ops across the barrier (rule #18/#21).
__device__ __forceinline__ void lgkm_bar() {
    asm volatile("s_waitcnt lgkmcnt(0)" ::: "memory");
    __builtin_amdgcn_s_barrier();
    asm volatile("" ::: "memory");
}

// ---------------- K0: Q = LN(mu) @ Wq + bq  -> Q[64][256] fp32 ----------------
__global__ void k_q(const float* __restrict__ mu, const float* __restrict__ g,
                    const float* __restrict__ bb, const float* __restrict__ Wq,
                    const float* __restrict__ bq, float* __restrict__ Q) {
    __shared__ float nrm[DIM];
    __shared__ float red1[4], red2[4];
    const int k = blockIdx.x, t = threadIdx.x;
    float x = mu[k * DIM + t];
    float s = x;
    #pragma unroll
    for (int o = 1; o <= 32; o <<= 1) s += __shfl_xor(s, o);
    if ((t & 63) == 0) red1[t >> 6] = s;
    __syncthreads();
    const float mean = (red1[0] + red1[1] + red1[2] + red1[3]) * (1.0f / DIM);
    const float d = x - mean;
    float vs = d * d;
    #pragma unroll
    for (int o = 1; o <= 32; o <<= 1) vs += __shfl_xor(vs, o);
    if ((t & 63) == 0) red2[t >> 6] = vs;
    __syncthreads();
    const float var = (red2[0] + red2[1] + red2[2] + red2[3]) * (1.0f / DIM);
    nrm[t] = d * rsqrtf(var + 1e-5f) * g[t] + bb[t];
    __syncthreads();
    float acc = bq[t];
    for (int c = 0; c < DIM; ++c) acc += nrm[c] * Wq[c * DIM + t];
    Q[k * DIM + t] = acc;
}

// ---- K1: fold scores matrix + transpose. W2T[n][c] (bf16, c contiguous) ----
__global__ void k_fold(const float* __restrict__ Q, const float* __restrict__ Wk,
                       const float* __restrict__ bk, const float* __restrict__ Wv,
                       const float* __restrict__ bv,
                       unsigned short* __restrict__ W2T, float* __restrict__ b2) {
    const int n = blockIdx.x, t = threadIdx.x;
    __shared__ float q[DH];
    if (n < 256) {
        const int h = n >> 6, k = n & 63;
        if (t < DH) q[t] = Q[k * DIM + h * DH + t];
        __syncthreads();
        float acc = 0.f;
        #pragma unroll 8
        for (int d0 = 0; d0 < DH; ++d0) acc += Wk[t * DIM + h * DH + d0] * q[d0];
        W2T[n * 256 + t] = f2bf(acc * 0.125f);
        if (t == 0) {
            float ba = 0.f;
            for (int d0 = 0; d0 < DH; ++d0) ba += bk[h * DH + d0] * q[d0];
            b2[n] = ba * 0.125f;
        }
    } else {
        const int col = n - 256;
        W2T[n * 256 + t] = f2bf(Wv[t * DIM + col]);
        if (t == 0) b2[n] = bv[col];
    }
}

// ======== K2: pipelined main kernel, raw barriers, no vmem drains ========
// Grid 256 = 4b x 64chunks (512 rows = 16 tiles of 32), 1024 thr = 16 waves.
// Same math/swizzles as round 8. Changes:
//  - raw s_barrier + lgkmcnt-only (pf global loads stay in flight across
//    barriers; consumed at X-stage write where compiler inserts vmcnt wait)
//  - A/V double-buffered (tb) -> PV(t-1) runs BEFORE the barrier, adjacent
//    to Y-GEMM(t)'s MFMA cluster
//  - s_setprio(1) around MFMA clusters (score/V role-split exists -> T5 regime)
// LDS (100352 B): xbuf0 @0, xbuf1 @16K, A dbuf @32K (2x16K), V dbuf @64K
// (2x16K), Ssc @96K (tb-indexed, 2048 B).
// Per tile t (tb=t&1): [A] issue pf(t+1); [B] Y-GEMM(t); [C] softmax->Ssc[tb];
// [PV(t-1)] from A/V[tb^1]; lgkm_bar; [E] read Ssc[tb], write A/V[tb],
// write xbuf[tb^1] from pf; lgkm_bar.  Epilogue: PV(15), stores (no atomics).
__global__ __launch_bounds__(1024)
void k_main_v2(const float* __restrict__ X, const unsigned short* __restrict__ W2T,
               const float* __restrict__ b2, float* __restrict__ num_p,
               float* __restrict__ den_p) {
    extern __shared__ __align__(16) unsigned char smem[];
    const int AB = 32768, VB = 65536, SB = 98304;
    const int tid  = threadIdx.x;
    const int lane = tid & 63;
    const int wid  = tid >> 6;
    const int l15  = lane & 15;
    const int lhi  = lane >> 4;
    const int bid   = blockIdx.x;
    const int b     = bid >> 6;
    const int chunk = bid & 63;
    const float* Xg = X + ((size_t)(b * SEQ + chunk * 512)) * DIM;

    const bool is_score = wid < 8;
    const int h_sc  = wid >> 1;
    const int sh    = wid & 1;
    const int vg    = wid - 8;
    const int h_v   = vg >> 1;
    const int nbase = wid * 32;
    const int hp = wid >> 2;
    const int dq = wid & 3;

    bf16x8 bfr[8][2];
    #pragma unroll
    for (int ks = 0; ks < 8; ++ks)
        #pragma unroll
        for (int ni = 0; ni < 2; ++ni)
            bfr[ks][ni] = *(const bf16x8*)(W2T + (size_t)(nbase + ni * 16 + l15) * 256
                                           + ks * 32 + lhi * 8);
    float bias[2];
    #pragma unroll
    for (int ni = 0; ni < 2; ++ni) bias[ni] = b2[nbase + ni * 16 + l15];

    f32x4 pv[4];
    #pragma unroll
    for (int i = 0; i < 4; ++i) pv[i] = (f32x4){0.f, 0.f, 0.f, 0.f};
    float den_acc[2] = {0.f, 0.f};

    float4 pf[2];
    // ---- prologue: stage tile 0 ----
    #pragma unroll
    for (int j = 0; j < 2; ++j) {
        const int f = j * 1024 + tid;
        pf[j] = *(const float4*)(Xg + (f >> 6) * DIM + (f & 63) * 4);
    }
    #pragma unroll
    for (int j = 0; j < 2; ++j) {
        const int f = j * 1024 + tid;
        const int row = f >> 6, c4 = f & 63;
        const int byte = row * 512 + ((c4 * 8) ^ ((row & 7) << 4));
        *(uint2*)(smem + byte) = make_uint2(f2bf2(pf[j].x, pf[j].y), f2bf2(pf[j].z, pf[j].w));
    }
    lgkm_bar();

    for (int t = 0; t < 16; ++t) {
        const int tb = t & 1;
        const unsigned char* xbuf = smem + tb * 16384;

        // ---- [A] issue next-tile loads (stay in flight across barrier 1) ----
        if (t < 15) {
            const float* Xt = Xg + (size_t)(t + 1) * 32 * DIM;
            #pragma unroll
            for (int j = 0; j < 2; ++j) {
                const int f = j * 1024 + tid;
                pf[j] = *(const float4*)(Xt + (f >> 6) * DIM + (f & 63) * 4);
            }
        }

        // ---- [B] Y-GEMM: 32 rows x 32 cols, B from registers ----
        f32x4 acc[2][2];
        #pragma unroll
        for (int si = 0; si < 2; ++si)
            #pragma unroll
            for (int ni = 0; ni < 2; ++ni)
                acc[si][ni] = (f32x4){bias[ni], bias[ni], bias[ni], bias[ni]};
        __builtin_amdgcn_s_setprio(1);
        #pragma unroll
        for (int ks = 0; ks < 8; ++ks) {
            #pragma unroll
            for (int si = 0; si < 2; ++si) {
                const int row  = si * 16 + l15;
                const int byte = row * 512 + ((ks * 64 + lhi * 16) ^ ((row & 7) << 4));
                const bf16x8 afr = *(const bf16x8*)(xbuf + byte);
                #pragma unroll
                for (int ni = 0; ni < 2; ++ni)
                    acc[si][ni] = __builtin_amdgcn_mfma_f32_16x16x32_bf16(
                        afr, bfr[ks][ni], acc[si][ni], 0, 0, 0);
            }
        }
        __builtin_amdgcn_s_setprio(0);

        // ---- [C] exp (no max) + partial slot-sums -> Ssc[tb] ----
        if (is_score) {
            #pragma unroll
            for (int si = 0; si < 2; ++si) {
                #pragma unroll
                for (int ni = 0; ni < 2; ++ni)
                    #pragma unroll
                    for (int r = 0; r < 4; ++r)
                        acc[si][ni][r] = __expf(acc[si][ni][r]);
                #pragma unroll
                for (int r = 0; r < 4; ++r) {
                    float p = acc[si][0][r] + acc[si][1][r];
                    p += __shfl_xor(p, 1);
                    p += __shfl_xor(p, 2);
                    p += __shfl_xor(p, 4);
                    p += __shfl_xor(p, 8);
                    if (l15 == 0)
                        *(float*)(smem + SB + (((tb * 4 + h_sc) * 2 + sh) * 32
                                               + si * 16 + lhi * 4 + r) * 4) = p;
                }
            }
        }

        // ---- [PV(t-1)] from A/V buffer tb^1 (written+published last tile) ----
        if (t > 0) {
            const int pb = tb ^ 1;
            bf16x8 afr[4];
            #pragma unroll
            for (int mi = 0; mi < 4; ++mi) {
                const int k = mi * 16 + l15;
                afr[mi] = *(const bf16x8*)(smem + AB + pb * 16384 + (hp * 64 + k) * 64
                                           + ((lhi * 16) ^ (((k >> 1) & 3) << 4)));
            }
            const int d = hp * 64 + dq * 16 + l15;
            const bf16x8 vfr = *(const bf16x8*)(smem + VB + pb * 16384 + d * 64
                                                + ((lhi * 16) ^ (((d >> 1) & 3) << 4)));
            __builtin_amdgcn_s_setprio(1);
            #pragma unroll
            for (int mi = 0; mi < 4; ++mi)
                pv[mi] = __builtin_amdgcn_mfma_f32_16x16x32_bf16(afr[mi], vfr, pv[mi], 0, 0, 0);
            __builtin_amdgcn_s_setprio(0);
        }

        // ---- barrier 1: Ssc visible; pf loads REMAIN in flight ----
        lgkm_bar();

        // ---- [E] read Ssc[tb]; write A/V[tb]; write xbuf[tb^1] from pf ----
        {
            const int hh = is_score ? h_sc : h_v;
            #pragma unroll
            for (int si = 0; si < 2; ++si) {
                const int sbase = SB + ((tb * 4 + hh) * 2) * 128 + (si * 16 + lhi * 4) * 4;
                const f32x4 s0 = *(const f32x4*)(smem + sbase);
                const f32x4 s1 = *(const f32x4*)(smem + sbase + 128);
                float sinv[4];
                #pragma unroll
                for (int r = 0; r < 4; ++r) sinv[r] = __builtin_amdgcn_rcpf(s0[r] + s1[r]);
                if (is_score) {
                    #pragma unroll
                    for (int ni = 0; ni < 2; ++ni) {
                        den_acc[ni] += acc[si][ni][0] * sinv[0] + acc[si][ni][1] * sinv[1]
                                     + acc[si][ni][2] * sinv[2] + acc[si][ni][3] * sinv[3];
                        const int k = sh * 32 + ni * 16 + l15;
                        const int byte = AB + tb * 16384 + (h_sc * 64 + k) * 64
                                       + ((si * 32 + lhi * 8) ^ (((k >> 1) & 3) << 4));
                        *(uint2*)(smem + byte) = make_uint2(
                            f2bf2(acc[si][ni][0], acc[si][ni][1]),
                            f2bf2(acc[si][ni][2], acc[si][ni][3]));
                    }
                } else {
                    #pragma unroll
                    for (int ni = 0; ni < 2; ++ni) {
                        const int d = vg * 32 + ni * 16 + l15;
                        const int byte = VB + tb * 16384 + d * 64
                                       + ((si * 32 + lhi * 8) ^ (((d >> 1) & 3) << 4));
                        *(uint2*)(smem + byte) = make_uint2(
                            f2bf2(acc[si][ni][0] * sinv[0], acc[si][ni][1] * sinv[1]),
                            f2bf2(acc[si][ni][2] * sinv[2], acc[si][ni][3] * sinv[3]));
                    }
                }
            }
        }
        if (t < 15) {
            unsigned char* nbuf = smem + (tb ^ 1) * 16384;
            #pragma unroll
            for (int j = 0; j < 2; ++j) {
                const int f = j * 1024 + tid;
                const int row = f >> 6, c4 = f & 63;
                const int byte = row * 512 + ((c4 * 8) ^ ((row & 7) << 4));
                *(uint2*)(nbuf + byte) = make_uint2(f2bf2(pf[j].x, pf[j].y),
                                                    f2bf2(pf[j].z, pf[j].w));
            }
        }

        // ---- barrier 2: A/V[tb] + xbuf(t+1) visible ----
        lgkm_bar();
    }

    // ---- final PV(15) from A/V buffer 1 ----
    {
        bf16x8 afr[4];
        #pragma unroll
        for (int mi = 0; mi < 4; ++mi) {
            const int k = mi * 16 + l15;
            afr[mi] = *(const bf16x8*)(smem + AB + 16384 + (hp * 64 + k) * 64
                                       + ((lhi * 16) ^ (((k >> 1) & 3) << 4)));
        }
        const int d = hp * 64 + dq * 16 + l15;
        const bf16x8 vfr = *(const bf16x8*)(smem + VB + 16384 + d * 64
                                            + ((lhi * 16) ^ (((d >> 1) & 3) << 4)));
        #pragma unroll
        for (int mi = 0; mi < 4; ++mi)
            pv[mi] = __builtin_amdgcn_mfma_f32_16x16x32_bf16(afr[mi], vfr, pv[mi], 0, 0, 0);
    }

    // ---- epilogue: plain coalesced partial stores, NO atomics ----
    float* np = num_p + (size_t)bid * 16384 + hp * 4096;
    #pragma unroll
    for (int mi = 0; mi < 4; ++mi)
        #pragma unroll
        for (int r = 0; r < 4; ++r)
            np[(mi * 16 + lhi * 4 + r) * 64 + dq * 16 + l15] = pv[mi][r];
    if (is_score) {
        #pragma unroll
        for (int ni = 0; ni < 2; ++ni) {
            float v = den_acc[ni];
            v += __shfl_xor(v, 16);
            v += __shfl_xor(v, 32);
            if (lhi == 0)
                den_p[(size_t)bid * 256 + h_sc * 64 + sh * 32 + ni * 16 + l15] = v;
        }
    }
}

// ---- K3: reduce 64 chunk-partials; LN ----
__global__ void k_final_part(const float* __restrict__ num_p, const float* __restrict__ den_p,
                             const float* __restrict__ ga, const float* __restrict__ gb,
                             float* __restrict__ out) {
    __shared__ float red1[4], red2[4];
    const int b = blockIdx.x >> 6, k = blockIdx.x & 63;
    const int t = threadIdx.x;
    const int h = t >> 6, dd = t & 63;
    float nsum = 0.f, dsum = 0.f;
    #pragma unroll 8
    for (int c = 0; c < 64; ++c) {
        const size_t bid = (size_t)(b * 64 + c);
        nsum += num_p[bid * 16384 + h * 4096 + k * 64 + dd];
        dsum += den_p[bid * 256 + h * 64 + k];
    }
    const float val = nsum / (dsum + 1e-20f);
    float s = val;
    #pragma unroll
    for (int o = 1; o <= 32; o <<= 1) s += __shfl_xor(s, o);
    if ((t & 63) == 0) red1[t >> 6] = s;
    __syncthreads();
    const float mean = (red1[0] + red1[1] + red1[2] + red1[3]) * (1.0f / DIM);
    const float d = val - mean;
    float vs = d * d;
    #pragma unroll
    for (int o = 1; o <= 32; o <<= 1) vs += __shfl_xor(vs, o);
    if ((t & 63) == 0) red2[t >> 6] = vs;
    __syncthreads();
    const float var = (red2[0] + red2[1] + red2[2] + red2[3]) * (1.0f / DIM);
    out[(size_t)(b * NKS + k) * DIM + t] = d * rsqrtf(var + 1e-5f) * ga[t] + gb[t];
}

extern "C" void kernel_launch(void* const* d_in, const int* in_sizes, int n_in,
                              void* d_out, int out_size, void* d_ws, size_t ws_size,
                              hipStream_t stream) {
    const float* X      = (const float*)d_in[0];
    const float* mu     = (const float*)d_in[1];
    const float* ln_s_g = (const float*)d_in[2];
    const float* ln_s_b = (const float*)d_in[3];
    const float* Wq     = (const float*)d_in[4];
    const float* bq     = (const float*)d_in[5];
    const float* Wk     = (const float*)d_in[6];
    const float* bk     = (const float*)d_in[7];
    const float* Wv     = (const float*)d_in[8];
    const float* bv     = (const float*)d_in[9];
    const float* ln_a_g = (const float*)d_in[10];
    const float* ln_a_b = (const float*)d_in[11];
    float* out = (float*)d_out;

    char* ws = (char*)d_ws;
    float*          Q     = (float*)(ws);                    //  65536 B
    unsigned short* W2T   = (unsigned short*)(ws + 65536);   // 262144 B
    float*          b2    = (float*)(ws + 327680);           //   2048 B
    float*          num_p = (float*)(ws + 329728);           // 16 MiB (256 x 64KB)
    float*          den_p = (float*)(ws + 329728 + 16777216);// 256 KiB

    hipFuncSetAttribute((const void*)k_main_v2,
                        hipFuncAttributeMaxDynamicSharedMemorySize, 100352);
    hipLaunchKernelGGL(k_q,    dim3(64),  dim3(256), 0, stream, mu, ln_s_g, ln_s_b, Wq, bq, Q);
    hipLaunchKernelGGL(k_fold, dim3(512), dim3(256), 0, stream, Q, Wk, bk, Wv, bv, W2T, b2);
    hipLaunchKernelGGL(k_main_v2, dim3(256), dim3(1024), 100352, stream,
                       X, W2T, b2, num_p, den_p);
    hipLaunchKernelGGL(k_final_part, dim3(256), dim3(256), 0, stream,
                       num_p, den_p, ln_a_g, ln_a_b, out);
}

// Round 10
// 130.154 us; speedup vs baseline: 1.3051x; 1.3051x over previous
//
#include <hip/hip_runtime.h>
#include <hip/hip_bf16.h>

#define DIM   256
#define DH    64
#define NKS   64      // K_SLOTS
#define NH    4       // HEADS
#define SEQ   32768

typedef float f32x4  __attribute__((ext_vector_type(4)));
typedef short bf16x8 __attribute__((ext_vector_type(8)));

__device__ __forceinline__ unsigned short f2bf(float f) {
    union { __hip_bfloat16 b; unsigned short u; } v;
    v.b = __float2bfloat16(f);
    return v.u;
}
__device__ __forceinline__ unsigned int f2bf2(float lo, float hi) {
    return (unsigned int)f2bf(lo) | ((unsigned int)f2bf(hi) << 16);
}

// ---------------- K0: Q = LN(mu) @ Wq + bq  -> Q[64][256] fp32 ----------------
__global__ void k_q(const float* __restrict__ mu, const float* __restrict__ g,
                    const float* __restrict__ bb, const float* __restrict__ Wq,
                    const float* __restrict__ bq, float* __restrict__ Q) {
    __shared__ float nrm[DIM];
    __shared__ float red1[4], red2[4];
    const int k = blockIdx.x, t = threadIdx.x;
    float x = mu[k * DIM + t];
    float s = x;
    #pragma unroll
    for (int o = 1; o <= 32; o <<= 1) s += __shfl_xor(s, o);
    if ((t & 63) == 0) red1[t >> 6] = s;
    __syncthreads();
    const float mean = (red1[0] + red1[1] + red1[2] + red1[3]) * (1.0f / DIM);
    const float d = x - mean;
    float vs = d * d;
    #pragma unroll
    for (int o = 1; o <= 32; o <<= 1) vs += __shfl_xor(vs, o);
    if ((t & 63) == 0) red2[t >> 6] = vs;
    __syncthreads();
    const float var = (red2[0] + red2[1] + red2[2] + red2[3]) * (1.0f / DIM);
    nrm[t] = d * rsqrtf(var + 1e-5f) * g[t] + bb[t];
    __syncthreads();
    float acc = bq[t];
    for (int c = 0; c < DIM; ++c) acc += nrm[c] * Wq[c * DIM + t];
    Q[k * DIM + t] = acc;
}

// ---- K1: fold scores matrix + transpose. W2T[n][c] (bf16, c contiguous) ----
__global__ void k_fold(const float* __restrict__ Q, const float* __restrict__ Wk,
                       const float* __restrict__ bk, const float* __restrict__ Wv,
                       const float* __restrict__ bv,
                       unsigned short* __restrict__ W2T, float* __restrict__ b2) {
    const int n = blockIdx.x, t = threadIdx.x;
    __shared__ float q[DH];
    if (n < 256) {
        const int h = n >> 6, k = n & 63;
        if (t < DH) q[t] = Q[k * DIM + h * DH + t];
        __syncthreads();
        float acc = 0.f;
        #pragma unroll 8
        for (int d0 = 0; d0 < DH; ++d0) acc += Wk[t * DIM + h * DH + d0] * q[d0];
        W2T[n * 256 + t] = f2bf(acc * 0.125f);
        if (t == 0) {
            float ba = 0.f;
            for (int d0 = 0; d0 < DH; ++d0) ba += bk[h * DH + d0] * q[d0];
            b2[n] = ba * 0.125f;
        }
    } else {
        const int col = n - 256;
        W2T[n * 256 + t] = f2bf(Wv[t * DIM + col]);
        if (t == 0) b2[n] = bv[col];
    }
}

// ======== PASS 1: k_w — scores + softmax(k); store W^T bf16 + den partials ========
// Grid 512 = 4b x 128chunks (256 rows = 8 tiles of 32), 512 thr = 8 waves.
// Wave wid = (h=wid>>1, sh=wid&1): 32 score cols (64-reg B-panel).
// ~114 regs/lane -> 4 waves/SIMD -> 2 blocks/CU (the structural fix: 16-wave
// blocks can never double-occupy; 8-wave blocks at <=128 regs can).
// LDS 34816: Xbuf dbuf 2x16K @0, Ssc @32768 ([2tb][4h][2sh][32row] f32, 2KB).
// W^T[b][h][k][s] (s contiguous!) so pass 2's PV A-operand is a plain
// contiguous 8B global load (K=32 A-layout: row=l15, k(s)=lhi*8+i).
__global__ __launch_bounds__(512)
void k_w(const float* __restrict__ X, const unsigned short* __restrict__ W2T,
         const float* __restrict__ b2, unsigned short* __restrict__ WT,
         float* __restrict__ den_p) {
    extern __shared__ __align__(16) unsigned char smem[];
    const int SB = 32768;
    const int tid  = threadIdx.x;
    const int lane = tid & 63;
    const int wid  = tid >> 6;
    const int l15  = lane & 15;
    const int lhi  = lane >> 4;
    const int bid   = blockIdx.x;
    const int b     = bid >> 7;
    const int chunk = bid & 127;
    const float* Xg = X + ((size_t)(b * SEQ + chunk * 256)) * DIM;

    const int h  = wid >> 1;
    const int sh = wid & 1;
    const int nbase = wid * 32;

    bf16x8 bfr[8][2];
    #pragma unroll
    for (int ks = 0; ks < 8; ++ks)
        #pragma unroll
        for (int ni = 0; ni < 2; ++ni)
            bfr[ks][ni] = *(const bf16x8*)(W2T + (size_t)(nbase + ni * 16 + l15) * 256
                                           + ks * 32 + lhi * 8);
    float bias[2];
    #pragma unroll
    for (int ni = 0; ni < 2; ++ni) bias[ni] = b2[nbase + ni * 16 + l15];

    float den_acc[2] = {0.f, 0.f};

    float4 pf[4];
    // ---- prologue: stage tile 0 (32 rows) ----
    #pragma unroll
    for (int j = 0; j < 4; ++j) {
        const int f = j * 512 + tid;
        pf[j] = *(const float4*)(Xg + (f >> 6) * DIM + (f & 63) * 4);
    }
    #pragma unroll
    for (int j = 0; j < 4; ++j) {
        const int f = j * 512 + tid;
        const int row = f >> 6, c4 = f & 63;
        const int byte = row * 512 + ((c4 * 8) ^ ((row & 7) << 4));
        *(uint2*)(smem + byte) = make_uint2(f2bf2(pf[j].x, pf[j].y), f2bf2(pf[j].z, pf[j].w));
    }
    __syncthreads();

    for (int t = 0; t < 8; ++t) {
        const int tb = t & 1;
        const unsigned char* xbuf = smem + tb * 16384;

        if (t < 7) {
            const float* Xt = Xg + (size_t)(t + 1) * 32 * DIM;
            #pragma unroll
            for (int j = 0; j < 4; ++j) {
                const int f = j * 512 + tid;
                pf[j] = *(const float4*)(Xt + (f >> 6) * DIM + (f & 63) * 4);
            }
        }

        // ---- score GEMM ----
        f32x4 acc[2][2];
        #pragma unroll
        for (int si = 0; si < 2; ++si)
            #pragma unroll
            for (int ni = 0; ni < 2; ++ni)
                acc[si][ni] = (f32x4){bias[ni], bias[ni], bias[ni], bias[ni]};
        #pragma unroll
        for (int ks = 0; ks < 8; ++ks) {
            #pragma unroll
            for (int si = 0; si < 2; ++si) {
                const int row  = si * 16 + l15;
                const int byte = row * 512 + ((ks * 64 + lhi * 16) ^ ((row & 7) << 4));
                const bf16x8 afr = *(const bf16x8*)(xbuf + byte);
                #pragma unroll
                for (int ni = 0; ni < 2; ++ni)
                    acc[si][ni] = __builtin_amdgcn_mfma_f32_16x16x32_bf16(
                        afr, bfr[ks][ni], acc[si][ni], 0, 0, 0);
            }
        }

        // ---- exp (no max; scores ~N(0,~0.1), proven rounds 5-8) + partial sums ----
        #pragma unroll
        for (int si = 0; si < 2; ++si) {
            #pragma unroll
            for (int ni = 0; ni < 2; ++ni)
                #pragma unroll
                for (int r = 0; r < 4; ++r)
                    acc[si][ni][r] = __expf(acc[si][ni][r]);
            #pragma unroll
            for (int r = 0; r < 4; ++r) {
                float p = acc[si][0][r] + acc[si][1][r];
                p += __shfl_xor(p, 1);
                p += __shfl_xor(p, 2);
                p += __shfl_xor(p, 4);
                p += __shfl_xor(p, 8);
                if (l15 == 0)
                    *(float*)(smem + SB + (((tb * 4 + h) * 2 + sh) * 32
                                           + si * 16 + lhi * 4 + r) * 4) = p;
            }
        }
        __syncthreads();

        // ---- W = exp/rowsum; den partial; store W^T; stage next X ----
        const int srow = chunk * 256 + t * 32;
        #pragma unroll
        for (int si = 0; si < 2; ++si) {
            const int sbase = SB + ((tb * 4 + h) * 2) * 128 + (si * 16 + lhi * 4) * 4;
            const f32x4 s0 = *(const f32x4*)(smem + sbase);
            const f32x4 s1 = *(const f32x4*)(smem + sbase + 128);
            float sinv[4];
            #pragma unroll
            for (int r = 0; r < 4; ++r) sinv[r] = 1.0f / (s0[r] + s1[r]);
            #pragma unroll
            for (int ni = 0; ni < 2; ++ni) {
                const float w0 = acc[si][ni][0] * sinv[0], w1 = acc[si][ni][1] * sinv[1];
                const float w2 = acc[si][ni][2] * sinv[2], w3 = acc[si][ni][3] * sinv[3];
                den_acc[ni] += (w0 + w1) + (w2 + w3);
                const size_t row = (size_t)((b * 4 + h) * 64 + sh * 32 + ni * 16 + l15);
                *(uint2*)(WT + row * SEQ + srow + si * 16 + lhi * 4) =
                    make_uint2(f2bf2(w0, w1), f2bf2(w2, w3));
            }
        }
        if (t < 7) {
            unsigned char* nbuf = smem + (tb ^ 1) * 16384;
            #pragma unroll
            for (int j = 0; j < 4; ++j) {
                const int f = j * 512 + tid;
                const int row = f >> 6, c4 = f & 63;
                const int byte = row * 512 + ((c4 * 8) ^ ((row & 7) << 4));
                *(uint2*)(nbuf + byte) = make_uint2(f2bf2(pf[j].x, pf[j].y),
                                                    f2bf2(pf[j].z, pf[j].w));
            }
        }
        __syncthreads();
    }

    // ---- den partial store (no atomics) ----
    #pragma unroll
    for (int ni = 0; ni < 2; ++ni) {
        float v = den_acc[ni];
        v += __shfl_xor(v, 16);
        v += __shfl_xor(v, 32);
        if (lhi == 0)
            den_p[(size_t)bid * 256 + wid * 32 + ni * 16 + l15] = v;
    }
}

// ======== PASS 2: k_pv — V on the fly; num += W^T · V (A-frags from global) ========
// Grid 512 = 4b x 128chunks (256 rows = 16 tiles of 16 = 8 pairs), 512 thr.
// Wave wid: V role = 32 V-cols (vbase=256+wid*32); PV role = (h=wid>>1, khalf=wid&1),
// covering 32 k x 64 d.  B-panel: ks0-3 persistent (32 regs) + ks4-7 streamed
// from L2 per tile.  pv[2][4]=32, af[2]=8, pf[2]=8 -> ~120 regs -> 2 blocks/CU.
// PV K=32 over a PAIR of 16-row tiles: A-frag = contiguous dwordx4 from WT
// (k=kh*32+mi*16+l15, s=P*32+lhi*8 — exact 16x16x32 A layout, transpose-free);
// B-frag = Vbuf[c][s] bf16 (round-8-proven layout+swizzle).
// LDS 49152: Xbuf dbuf 2x8K @0, Vbuf dbuf 2x16K @16384.
__global__ __launch_bounds__(512)
void k_pv(const float* __restrict__ X, const unsigned short* __restrict__ W2T,
          const float* __restrict__ b2, const unsigned short* __restrict__ WT,
          float* __restrict__ num_p) {
    extern __shared__ __align__(16) unsigned char smem[];
    const int VB = 16384;
    const int tid  = threadIdx.x;
    const int lane = tid & 63;
    const int wid  = tid >> 6;
    const int l15  = lane & 15;
    const int lhi  = lane >> 4;
    const int bid   = blockIdx.x;
    const int b     = bid >> 7;
    const int chunk = bid & 127;
    const float* Xg = X + ((size_t)(b * SEQ + chunk * 256)) * DIM;

    const int h  = wid >> 1;
    const int kh = wid & 1;
    const int vbase = 256 + wid * 32;

    bf16x8 bfr_lo[4][2];
    #pragma unroll
    for (int ks = 0; ks < 4; ++ks)
        #pragma unroll
        for (int nj = 0; nj < 2; ++nj)
            bfr_lo[ks][nj] = *(const bf16x8*)(W2T + (size_t)(vbase + nj * 16 + l15) * 256
                                              + ks * 32 + lhi * 8);
    float bias[2];
    #pragma unroll
    for (int nj = 0; nj < 2; ++nj) bias[nj] = b2[vbase + nj * 16 + l15];

    f32x4 pv[2][4];
    #pragma unroll
    for (int mi = 0; mi < 2; ++mi)
        #pragma unroll
        for (int nj = 0; nj < 4; ++nj) pv[mi][nj] = (f32x4){0.f, 0.f, 0.f, 0.f};

    bf16x8 af[2];
    float4 pf[2];
    // ---- prologue: stage tile 0 (16 rows) ----
    #pragma unroll
    for (int j = 0; j < 2; ++j) {
        const int f = j * 512 + tid;
        pf[j] = *(const float4*)(Xg + (f >> 6) * DIM + (f & 63) * 4);
    }
    #pragma unroll
    for (int j = 0; j < 2; ++j) {
        const int f = j * 512 + tid;
        const int row = f >> 6, c4 = f & 63;
        const int byte = row * 512 + ((c4 * 8) ^ ((row & 7) << 4));
        *(uint2*)(smem + byte) = make_uint2(f2bf2(pf[j].x, pf[j].y), f2bf2(pf[j].z, pf[j].w));
    }
    __syncthreads();

    for (int t = 0; t < 16; ++t) {
        const int P = t >> 1, half = t & 1, tb = t & 1, vb = P & 1;
        const unsigned char* xbuf = smem + tb * 8192;

        // ---- PV of pair P-1 (Vbuf[vb^1] complete, af loaded 2 tiles ago) ----
        if (half == 0 && P > 0) {
            bf16x8 vB[4];
            #pragma unroll
            for (int nj = 0; nj < 4; ++nj) {
                const int c = h * 64 + nj * 16 + l15;
                vB[nj] = *(const bf16x8*)(smem + VB + (vb ^ 1) * 16384 + c * 64
                                          + ((lhi * 16) ^ (((c >> 1) & 3) << 4)));
            }
            #pragma unroll
            for (int mi = 0; mi < 2; ++mi)
                #pragma unroll
                for (int nj = 0; nj < 4; ++nj)
                    pv[mi][nj] = __builtin_amdgcn_mfma_f32_16x16x32_bf16(
                        af[mi], vB[nj], pv[mi][nj], 0, 0, 0);
        }
        // ---- issue W^T A-frags for pair P (used at t+2; latency hidden) ----
        if (half == 0) {
            const int s0 = chunk * 256 + P * 32 + lhi * 8;
            #pragma unroll
            for (int mi = 0; mi < 2; ++mi) {
                const size_t row = (size_t)((b * 4 + h) * 64 + kh * 32 + mi * 16 + l15);
                af[mi] = *(const bf16x8*)(WT + row * SEQ + s0);
            }
        }
        // ---- prefetch next X tile ----
        if (t < 15) {
            const float* Xt = Xg + (size_t)(t + 1) * 16 * DIM;
            #pragma unroll
            for (int j = 0; j < 2; ++j) {
                const int f = j * 512 + tid;
                pf[j] = *(const float4*)(Xt + (f >> 6) * DIM + (f & 63) * 4);
            }
        }

        // ---- V-GEMM (16 rows x 32 cols): ks0-3 from regs, ks4-7 streamed L2 ----
        bf16x8 bh[4][2];
        #pragma unroll
        for (int ks = 0; ks < 4; ++ks)
            #pragma unroll
            for (int nj = 0; nj < 2; ++nj)
                bh[ks][nj] = *(const bf16x8*)(W2T + (size_t)(vbase + nj * 16 + l15) * 256
                                              + (ks + 4) * 32 + lhi * 8);
        f32x4 vacc[2];
        #pragma unroll
        for (int nj = 0; nj < 2; ++nj)
            vacc[nj] = (f32x4){bias[nj], bias[nj], bias[nj], bias[nj]};
        #pragma unroll
        for (int ks = 0; ks < 8; ++ks) {
            const int byte = l15 * 512 + ((ks * 64 + lhi * 16) ^ ((l15 & 7) << 4));
            const bf16x8 afr = *(const bf16x8*)(xbuf + byte);
            #pragma unroll
            for (int nj = 0; nj < 2; ++nj)
                vacc[nj] = __builtin_amdgcn_mfma_f32_16x16x32_bf16(
                    afr, ks < 4 ? bfr_lo[ks][nj] : bh[ks - 4][nj], vacc[nj], 0, 0, 0);
        }
        __syncthreads();

        // ---- write V half-rows into Vbuf[vb]; stage next X ----
        #pragma unroll
        for (int nj = 0; nj < 2; ++nj) {
            const int c = wid * 32 + nj * 16 + l15;
            const int byte = VB + vb * 16384 + c * 64
                           + ((half * 32 + lhi * 8) ^ (((c >> 1) & 3) << 4));
            *(uint2*)(smem + byte) = make_uint2(f2bf2(vacc[nj][0], vacc[nj][1]),
                                                f2bf2(vacc[nj][2], vacc[nj][3]));
        }
        if (t < 15) {
            unsigned char* nbuf = smem + (tb ^ 1) * 8192;
            #pragma unroll
            for (int j = 0; j < 2; ++j) {
                const int f = j * 512 + tid;
                const int row = f >> 6, c4 = f & 63;
                const int byte = row * 512 + ((c4 * 8) ^ ((row & 7) << 4));
                *(uint2*)(nbuf + byte) = make_uint2(f2bf2(pf[j].x, pf[j].y),
                                                    f2bf2(pf[j].z, pf[j].w));
            }
        }
        __syncthreads();
    }

    // ---- final PV (pair 7, Vbuf[1]) ----
    {
        bf16x8 vB[4];
        #pragma unroll
        for (int nj = 0; nj < 4; ++nj) {
            const int c = h * 64 + nj * 16 + l15;
            vB[nj] = *(const bf16x8*)(smem + VB + 16384 + c * 64
                                      + ((lhi * 16) ^ (((c >> 1) & 3) << 4)));
        }
        #pragma unroll
        for (int mi = 0; mi < 2; ++mi)
            #pragma unroll
            for (int nj = 0; nj < 4; ++nj)
                pv[mi][nj] = __builtin_amdgcn_mfma_f32_16x16x32_bf16(
                    af[mi], vB[nj], pv[mi][nj], 0, 0, 0);
    }

    // ---- store num partials (no atomics) ----
    #pragma unroll
    for (int mi = 0; mi < 2; ++mi)
        #pragma unroll
        for (int nj = 0; nj < 4; ++nj)
            #pragma unroll
            for (int r = 0; r < 4; ++r) {
                const int k = kh * 32 + mi * 16 + lhi * 4 + r;
                num_p[(((size_t)bid * 4 + h) * 64 + k) * 64 + nj * 16 + l15] = pv[mi][nj][r];
            }
}

// ---- K3: reduce 128 chunk-partials; S_hat = num/(den+eps); LN ----
__global__ void k_final2(const float* __restrict__ num_p, const float* __restrict__ den_p,
                         const float* __restrict__ ga, const float* __restrict__ gb,
                         float* __restrict__ out) {
    __shared__ float red1[4], red2[4];
    const int b = blockIdx.x >> 6, k = blockIdx.x & 63;
    const int t = threadIdx.x;
    const int h = t >> 6, dd = t & 63;
    float nsum = 0.f, dsum = 0.f;
    #pragma unroll 8
    for (int c = 0; c < 128; ++c) {
        const size_t bid = (size_t)(b * 128 + c);
        nsum += num_p[((bid * 4 + h) * 64 + k) * 64 + dd];
        dsum += den_p[bid * 256 + h * 64 + k];
    }
    const float val = nsum / (dsum + 1e-20f);
    float s = val;
    #pragma unroll
    for (int o = 1; o <= 32; o <<= 1) s += __shfl_xor(s, o);
    if ((t & 63) == 0) red1[t >> 6] = s;
    __syncthreads();
    const float mean = (red1[0] + red1[1] + red1[2] + red1[3]) * (1.0f / DIM);
    const float d = val - mean;
    float vs = d * d;
    #pragma unroll
    for (int o = 1; o <= 32; o <<= 1) vs += __shfl_xor(vs, o);
    if ((t & 63) == 0) red2[t >> 6] = vs;
    __syncthreads();
    const float var = (red2[0] + red2[1] + red2[2] + red2[3]) * (1.0f / DIM);
    out[(size_t)(b * NKS + k) * DIM + t] = d * rsqrtf(var + 1e-5f) * ga[t] + gb[t];
}

// ======== FALLBACK: round-8 fused kernel (proven 155us) if ws too small ========
__global__ __launch_bounds__(1024)
void k_main_part(const float* __restrict__ X, const unsigned short* __restrict__ W2T,
                 const float* __restrict__ b2, float* __restrict__ num_p,
                 float* __restrict__ den_p) {
    extern __shared__ __align__(16) unsigned char smem[];
    const int AB = 32768, VB = 49152, SB = 65536;
    const int tid  = threadIdx.x;
    const int lane = tid & 63;
    const int wid  = tid >> 6;
    const int l15  = lane & 15;
    const int lhi  = lane >> 4;
    const int bid   = blockIdx.x;
    const int b     = bid >> 6;
    const int chunk = bid & 63;
    const float* Xg = X + ((size_t)(b * SEQ + chunk * 512)) * DIM;
    const bool is_score = wid < 8;
    const int h_sc  = wid >> 1;
    const int sh    = wid & 1;
    const int vg    = wid - 8;
    const int h_v   = vg >> 1;
    const int nbase = wid * 32;
    const int hp = wid >> 2;
    const int dq = wid & 3;
    bf16x8 bfr[8][2];
    #pragma unroll
    for (int ks = 0; ks < 8; ++ks)
        #pragma unroll
        for (int ni = 0; ni < 2; ++ni)
            bfr[ks][ni] = *(const bf16x8*)(W2T + (size_t)(nbase + ni * 16 + l15) * 256
                                           + ks * 32 + lhi * 8);
    float bias[2];
    #pragma unroll
    for (int ni = 0; ni < 2; ++ni) bias[ni] = b2[nbase + ni * 16 + l15];
    f32x4 pv[4];
    #pragma unroll
    for (int i = 0; i < 4; ++i) pv[i] = (f32x4){0.f, 0.f, 0.f, 0.f};
    float den_acc[2] = {0.f, 0.f};
    float4 pf[2];
    #pragma unroll
    for (int j = 0; j < 2; ++j) {
        const int f = j * 1024 + tid;
        pf[j] = *(const float4*)(Xg + (f >> 6) * DIM + (f & 63) * 4);
    }
    #pragma unroll
    for (int j = 0; j < 2; ++j) {
        const int f = j * 1024 + tid;
        const int row = f >> 6, c4 = f & 63;
        const int byte = row * 512 + ((c4 * 8) ^ ((row & 7) << 4));
        *(uint2*)(smem + byte) = make_uint2(f2bf2(pf[j].x, pf[j].y), f2bf2(pf[j].z, pf[j].w));
    }
    __syncthreads();
    for (int t = 0; t < 16; ++t) {
        const int tb = t & 1;
        const unsigned char* xbuf = smem + tb * 16384;
        if (t < 15) {
            const float* Xt = Xg + (size_t)(t + 1) * 32 * DIM;
            #pragma unroll
            for (int j = 0; j < 2; ++j) {
                const int f = j * 1024 + tid;
                pf[j] = *(const float4*)(Xt + (f >> 6) * DIM + (f & 63) * 4);
            }
        }
        f32x4 acc[2][2];
        #pragma unroll
        for (int si = 0; si < 2; ++si)
            #pragma unroll
            for (int ni = 0; ni < 2; ++ni)
                acc[si][ni] = (f32x4){bias[ni], bias[ni], bias[ni], bias[ni]};
        #pragma unroll
        for (int ks = 0; ks < 8; ++ks) {
            #pragma unroll
            for (int si = 0; si < 2; ++si) {
                const int row  = si * 16 + l15;
                const int byte = row * 512 + ((ks * 64 + lhi * 16) ^ ((row & 7) << 4));
                const bf16x8 afr = *(const bf16x8*)(xbuf + byte);
                #pragma unroll
                for (int ni = 0; ni < 2; ++ni)
                    acc[si][ni] = __builtin_amdgcn_mfma_f32_16x16x32_bf16(
                        afr, bfr[ks][ni], acc[si][ni], 0, 0, 0);
            }
        }
        if (is_score) {
            #pragma unroll
            for (int si = 0; si < 2; ++si) {
                #pragma unroll
                for (int ni = 0; ni < 2; ++ni)
                    #pragma unroll
                    for (int r = 0; r < 4; ++r)
                        acc[si][ni][r] = __expf(acc[si][ni][r]);
                #pragma unroll
                for (int r = 0; r < 4; ++r) {
                    float p = acc[si][0][r] + acc[si][1][r];
                    p += __shfl_xor(p, 1);
                    p += __shfl_xor(p, 2);
                    p += __shfl_xor(p, 4);
                    p += __shfl_xor(p, 8);
                    if (l15 == 0)
                        *(float*)(smem + SB + (((tb * 4 + h_sc) * 2 + sh) * 32
                                               + si * 16 + lhi * 4 + r) * 4) = p;
                }
            }
        }
        __syncthreads();
        {
            const int hh = is_score ? h_sc : h_v;
            #pragma unroll
            for (int si = 0; si < 2; ++si) {
                const int sbase = SB + ((tb * 4 + hh) * 2) * 128 + (si * 16 + lhi * 4) * 4;
                const f32x4 s0 = *(const f32x4*)(smem + sbase);
                const f32x4 s1 = *(const f32x4*)(smem + sbase + 128);
                float sinv[4];
                #pragma unroll
                for (int r = 0; r < 4; ++r) sinv[r] = 1.0f / (s0[r] + s1[r]);
                if (is_score) {
                    #pragma unroll
                    for (int ni = 0; ni < 2; ++ni) {
                        den_acc[ni] += acc[si][ni][0] * sinv[0] + acc[si][ni][1] * sinv[1]
                                     + acc[si][ni][2] * sinv[2] + acc[si][ni][3] * sinv[3];
                        const int k = sh * 32 + ni * 16 + l15;
                        const int byte = AB + (h_sc * 64 + k) * 64
                                       + ((si * 32 + lhi * 8) ^ (((k >> 1) & 3) << 4));
                        *(uint2*)(smem + byte) = make_uint2(
                            f2bf2(acc[si][ni][0], acc[si][ni][1]),
                            f2bf2(acc[si][ni][2], acc[si][ni][3]));
                    }
                } else {
                    #pragma unroll
                    for (int ni = 0; ni < 2; ++ni) {
                        const int d = vg * 32 + ni * 16 + l15;
                        const int byte = VB + d * 64
                                       + ((si * 32 + lhi * 8) ^ (((d >> 1) & 3) << 4));
                        *(uint2*)(smem + byte) = make_uint2(
                            f2bf2(acc[si][ni][0] * sinv[0], acc[si][ni][1] * sinv[1]),
                            f2bf2(acc[si][ni][2] * sinv[2], acc[si][ni][3] * sinv[3]));
                    }
                }
            }
        }
        if (t < 15) {
            unsigned char* nbuf = smem + (tb ^ 1) * 16384;
            #pragma unroll
            for (int j = 0; j < 2; ++j) {
                const int f = j * 1024 + tid;
                const int row = f >> 6, c4 = f & 63;
                const int byte = row * 512 + ((c4 * 8) ^ ((row & 7) << 4));
                *(uint2*)(nbuf + byte) = make_uint2(f2bf2(pf[j].x, pf[j].y),
                                                    f2bf2(pf[j].z, pf[j].w));
            }
        }
        __syncthreads();
        {
            bf16x8 afr[4];
            #pragma unroll
            for (int mi = 0; mi < 4; ++mi) {
                const int k = mi * 16 + l15;
                afr[mi] = *(const bf16x8*)(smem + AB + (hp * 64 + k) * 64
                                           + ((lhi * 16) ^ (((k >> 1) & 3) << 4)));
            }
            const int d = hp * 64 + dq * 16 + l15;
            const bf16x8 vfr = *(const bf16x8*)(smem + VB + d * 64
                                                + ((lhi * 16) ^ (((d >> 1) & 3) << 4)));
            #pragma unroll
            for (int mi = 0; mi < 4; ++mi)
                pv[mi] = __builtin_amdgcn_mfma_f32_16x16x32_bf16(afr[mi], vfr, pv[mi], 0, 0, 0);
        }
    }
    float* np = num_p + (size_t)bid * 16384 + hp * 4096;
    #pragma unroll
    for (int mi = 0; mi < 4; ++mi)
        #pragma unroll
        for (int r = 0; r < 4; ++r)
            np[(mi * 16 + lhi * 4 + r) * 64 + dq * 16 + l15] = pv[mi][r];
    if (is_score) {
        #pragma unroll
        for (int ni = 0; ni < 2; ++ni) {
            float v = den_acc[ni];
            v += __shfl_xor(v, 16);
            v += __shfl_xor(v, 32);
            if (lhi == 0)
                den_p[(size_t)bid * 256 + h_sc * 64 + sh * 32 + ni * 16 + l15] = v;
        }
    }
}

__global__ void k_final_part(const float* __restrict__ num_p, const float* __restrict__ den_p,
                             const float* __restrict__ ga, const float* __restrict__ gb,
                             float* __restrict__ out) {
    __shared__ float red1[4], red2[4];
    const int b = blockIdx.x >> 6, k = blockIdx.x & 63;
    const int t = threadIdx.x;
    const int h = t >> 6, dd = t & 63;
    float nsum = 0.f, dsum = 0.f;
    #pragma unroll 8
    for (int c = 0; c < 64; ++c) {
        const size_t bid = (size_t)(b * 64 + c);
        nsum += num_p[bid * 16384 + h * 4096 + k * 64 + dd];
        dsum += den_p[bid * 256 + h * 64 + k];
    }
    const float val = nsum / (dsum + 1e-20f);
    float s = val;
    #pragma unroll
    for (int o = 1; o <= 32; o <<= 1) s += __shfl_xor(s, o);
    if ((t & 63) == 0) red1[t >> 6] = s;
    __syncthreads();
    const float mean = (red1[0] + red1[1] + red1[2] + red1[3]) * (1.0f / DIM);
    const float d = val - mean;
    float vs = d * d;
    #pragma unroll
    for (int o = 1; o <= 32; o <<= 1) vs += __shfl_xor(vs, o);
    if ((t & 63) == 0) red2[t >> 6] = vs;
    __syncthreads();
    const float var = (red2[0] + red2[1] + red2[2] + red2[3]) * (1.0f / DIM);
    out[(size_t)(b * NKS + k) * DIM + t] = d * rsqrtf(var + 1e-5f) * ga[t] + gb[t];
}

extern "C" void kernel_launch(void* const* d_in, const int* in_sizes, int n_in,
                              void* d_out, int out_size, void* d_ws, size_t ws_size,
                              hipStream_t stream) {
    const float* X      = (const float*)d_in[0];
    const float* mu     = (const float*)d_in[1];
    const float* ln_s_g = (const float*)d_in[2];
    const float* ln_s_b = (const float*)d_in[3];
    const float* Wq     = (const float*)d_in[4];
    const float* bq     = (const float*)d_in[5];
    const float* Wk     = (const float*)d_in[6];
    const float* bk     = (const float*)d_in[7];
    const float* Wv     = (const float*)d_in[8];
    const float* bv     = (const float*)d_in[9];
    const float* ln_a_g = (const float*)d_in[10];
    const float* ln_a_b = (const float*)d_in[11];
    float* out = (float*)d_out;

    char* ws = (char*)d_ws;
    float*          Q   = (float*)(ws);                    //  65536 B
    unsigned short* W2T = (unsigned short*)(ws + 65536);   // 262144 B
    float*          b2  = (float*)(ws + 327680);           //   2048 B

    hipLaunchKernelGGL(k_q,    dim3(64),  dim3(256), 0, stream, mu, ln_s_g, ln_s_b, Wq, bq, Q);
    hipLaunchKernelGGL(k_fold, dim3(512), dim3(256), 0, stream, Q, Wk, bk, Wv, bv, W2T, b2);

    // two-pass layout: WT 67.1MB @329728, num_p 33.5MB, den_p 512KB
    const size_t WT_OFF  = 329728;
    const size_t NUM_OFF = WT_OFF + (size_t)1024 * SEQ * 2;        // 67108864
    const size_t DEN_OFF = NUM_OFF + (size_t)512 * 16384 * 4;      // 33554432
    const size_t need2   = DEN_OFF + (size_t)512 * 256 * 4;

    if (ws_size >= need2) {
        unsigned short* WT    = (unsigned short*)(ws + WT_OFF);
        float*          num_p = (float*)(ws + NUM_OFF);
        float*          den_p = (float*)(ws + DEN_OFF);
        hipLaunchKernelGGL(k_w,  dim3(512), dim3(512), 34816, stream, X, W2T, b2, WT, den_p);
        hipLaunchKernelGGL(k_pv, dim3(512), dim3(512), 49152, stream, X, W2T, b2, WT, num_p);
        hipLaunchKernelGGL(k_final2, dim3(256), dim3(256), 0, stream,
                           num_p, den_p, ln_a_g, ln_a_b, out);
    } else {
        // round-8 fallback (17.1 MB)
        float* num_p = (float*)(ws + 329728);
        float* den_p = (float*)(ws + 329728 + 16777216);
        hipFuncSetAttribute((const void*)k_main_part,
                            hipFuncAttributeMaxDynamicSharedMemorySize, 67584);
        hipLaunchKernelGGL(k_main_part, dim3(256), dim3(1024), 67584, stream,
                           X, W2T, b2, num_p, den_p);
        hipLaunchKernelGGL(k_final_part, dim3(256), dim3(256), 0, stream,
                           num_p, den_p, ln_a_g, ln_a_b, out);
    }
}